// Round 1
// baseline (330.552 us; speedup 1.0000x reference)
//
#include <hip/hip_runtime.h>
#include <math.h>

// Problem constants (fixed by setup_inputs)
constexpr int B_ = 4, S_ = 8192, D_ = 1024, H_ = 1024, O_ = 1024;

typedef float f32x4  __attribute__((ext_vector_type(4)));
typedef float f32x16 __attribute__((ext_vector_type(16)));
typedef int   i32x4  __attribute__((ext_vector_type(4)));
typedef int   i32x8  __attribute__((ext_vector_type(8)));

__device__ __forceinline__ float softplusf(float x) {
    if (x > 20.f) return x;
    if (x < -20.f) return expf(x);
    return log1pf(expf(x));
}

// ---------------------------------------------------------------------------
// fp32 -> fp8 e4m3 conversion for x (scale 1) and w_in (scale 16, compensated
// by a 2^-4 e8m0 B-scale inside the MFMA). 8 elems/thread.
// ---------------------------------------------------------------------------
__global__ __launch_bounds__(256) void cvt_fp8_2(
    const float* __restrict__ srcA, unsigned char* __restrict__ dstA, int nA8,
    const float* __restrict__ srcB, unsigned char* __restrict__ dstB, int nB8) {
    int i = blockIdx.x * blockDim.x + threadIdx.x;
    const float* src; unsigned char* dst; float sc;
    if (i < nA8) { src = srcA; dst = dstA; sc = 1.f; }
    else { i -= nA8; if (i >= nB8) return; src = srcB; dst = dstB; sc = 16.f; }
    const float4* s = (const float4*)src + (size_t)i * 2;
    float4 a = s[0], b = s[1];
    int lo = __builtin_amdgcn_cvt_pk_fp8_f32(a.x * sc, a.y * sc, 0, false);
    lo     = __builtin_amdgcn_cvt_pk_fp8_f32(a.z * sc, a.w * sc, lo, true);
    int hi = __builtin_amdgcn_cvt_pk_fp8_f32(b.x * sc, b.y * sc, 0, false);
    hi     = __builtin_amdgcn_cvt_pk_fp8_f32(b.z * sc, b.w * sc, hi, true);
    ((int2*)dst)[i] = make_int2(lo, hi);
}

// ---------------------------------------------------------------------------
// Exact F in fp32 (one wave per (b,h)):
//   F = (1+e^{-i}) / ((1+e^{-f}) + (1+e^{-i}))  at s = S-1
// ---------------------------------------------------------------------------
__global__ __launch_bounds__(256) void f_exact(
    const float* __restrict__ x, const float* __restrict__ w_in,
    float* __restrict__ F_ws)
{
    const int lane = threadIdx.x & 63;
    const int pair = blockIdx.x * 4 + (threadIdx.x >> 6);   // 0..4095
    const int b = pair >> 10, h = pair & (H_ - 1);
    const float* xr = x + ((size_t)b * S_ + (S_ - 1)) * D_;
    const float* wf = w_in + (size_t)h * D_;
    const float* wi = wf + (size_t)H_ * D_;
    float sf = 0.f, si = 0.f;
    for (int k = lane; k < D_; k += 64) {
        float xv = xr[k];
        sf = fmaf(xv, wf[k], sf);
        si = fmaf(xv, wi[k], si);
    }
    #pragma unroll
    for (int off = 32; off > 0; off >>= 1) {
        sf += __shfl_xor(sf, off, 64);
        si += __shfl_xor(si, off, 64);
    }
    if (lane == 0) {
        float af1 = 1.f + expf(-sf), ai1 = 1.f + expf(-si);
        F_ws[(size_t)b * H_ + h] = ai1 / (af1 + ai1);
    }
}

// ---------------------------------------------------------------------------
// MX-fp8 MFMA GEMM (z = x @ w_in^T, 3 gates) fused with elementwise chain and
// s-reduction.
//   Round-N changes vs 331 µs baseline:
//   - Block tile BM=256 x BN=64 (was 128x64); each wave owns 4 m-tiles x 32h
//     x 3 gates = 12 MFMAs per chunk from 14 ds_read_b128 (was 6 from 10):
//     LDS bytes per MFMA-lane 26.7 -> 18.7, putting LDS read cost below the
//     12x17cy MFMA cost per round.
//   - T3/T4: raw s_barrier + counted s_waitcnt vmcnt(7); 2 chunks of
//     global_load_lds stay in flight across barriers (no vmcnt(0) drain in
//     the main loop). 2 barriers/chunk, prefetch issued 2 chunks ahead.
//   - T5: s_setprio(1) around the ds_read+MFMA cluster.
//   Staging layout unchanged: 64 B rows, 4 x 16 B slots, slot = q ^ ((row>>1)&3).
//   Swizzle term (row>>1)&3 == (l31>>1)&3 for all fragments -> fragment
//   addresses collapse to 4 base regs + immediates (keeps VGPR <= 256).
// ---------------------------------------------------------------------------
constexpr int BM = 256, BN = 64, BK = 64;          // BK in fp8 bytes
constexpr int ABYTES = BM * BK;                    // 16384
constexpr int BUF_BYTES = (BM + 3 * BN) * BK;      // 28672
constexpr int NX = B_ * S_ * D_;                   // xq bytes; wq = xq + NX

__global__ __launch_bounds__(256, 2) void gemm_fused_fp8(
    const unsigned char* __restrict__ xq, const unsigned char* __restrict__ wq,
    float* __restrict__ acc_ws)
{
    __shared__ __align__(16) unsigned char sbuf[2][BUF_BYTES];   // 56 KB dbuf
    __shared__ float colsum[BN];

    // decode: id = ((pl*16 + hb) * 8) + c ; panel = c*16 + pl
    // (16 h-tiles of one A panel -> same XCD under round-robin mod 8)
    const int id = blockIdx.x;
    const int c8 = id & 7;
    const int q  = id >> 3;
    const int hb = q & 15;
    const int pl = q >> 4;
    const int panel = c8 * 16 + pl;       // 0..127
    const int sb = panel & 31;
    const int b  = panel >> 5;

    const int h0   = hb * BN;
    const int s0   = sb * BM;
    const int tid  = threadIdx.x;
    const int lane = tid & 63;
    const int wid  = tid >> 6;
    const int wm   = wid >> 1;   // 0..1 : s offset wm*128
    const int wn   = wid & 1;    // 0..1 : h offset wn*32
    const int l31  = lane & 31;
    const int half = lane >> 5;  // k-half for MFMA operand

    if (tid < BN) colsum[tid] = 0.f;

    // --- staging: wave-load u = wid*7 + j; 64 lanes x 16B = 16 rows x 64B ---
    // u 0..15 = A chunks (16 rows each), u 16..27 = B chunks (gate (u-16)>>2).
    // LDS offset is u*1024 for ALL u (B region starts at 16384 = 16*1024).
    int goff[7];
    {
        const int rl = lane >> 2;        // row within 16-row chunk
        const int sp = lane & 3;         // dest 16B slot within 64B row
        const int qq = sp ^ ((rl >> 1) & 3);   // swizzled source slot
        #pragma unroll
        for (int j = 0; j < 7; ++j) {
            int u = wid * 7 + j;
            if (u < 16) {
                int row = u * 16 + rl;   // 0..255
                goff[j] = (b * S_ + s0 + row) * D_ + qq * 16;
            } else {
                int v = u - 16;          // gate g = v>>2, chunk = v&3
                int row = (v & 3) * 16 + rl;  // 0..63 within gate tile
                goff[j] = NX + (v >> 2) * (H_ * D_) + (h0 + row) * D_ + qq * 16;
            }
        }
    }
    const int wbase = wid * 7 * 1024;    // wave-uniform LDS chunk base

    // --- fragment byte-offsets: swizzle term is t/g-independent -----------
    const int g2 = (l31 >> 1) & 3;
    const int sA = ((half * 2) ^ g2) * 16;
    const int aof0  = (wm * 128 + l31) * 64 + sA;       // + t*2048
    const int aof0x = aof0 ^ 16;
    const int bof0  = ABYTES + (wn * 32 + l31) * 64 + sA;  // + g*4096
    const int bof0x = bof0 ^ 16;

    f32x16 acc[3][4] = {};   // [gate][m-tile]

    auto issue_loads = [&](int nxt) {
        #pragma unroll
        for (int j = 0; j < 7; ++j) {
            __builtin_amdgcn_global_load_lds(
                (const __attribute__((address_space(1))) void*)(xq + goff[j]),
                (__attribute__((address_space(3))) void*)(&sbuf[nxt][wbase + j * 1024]),
                16, 0, 0);
            goff[j] += BK;
        }
    };
    auto rd8 = [](const unsigned char* base, int o0, int o1) -> i32x8 {
        i32x4 lo = *(const i32x4*)(base + o0);
        i32x4 hi = *(const i32x4*)(base + o1);
        i32x8 r = {lo.x, lo.y, lo.z, lo.w, hi.x, hi.y, hi.z, hi.w};
        return r;
    };
    auto compute = [&](int cur) {
        const unsigned char* bp = &sbuf[cur][0];
        i32x8 af[4];
        #pragma unroll
        for (int t = 0; t < 4; ++t)
            af[t] = rd8(bp, aof0 + t * 2048, aof0x + t * 2048);
        #pragma unroll
        for (int g = 0; g < 3; ++g) {
            i32x8 bf = rd8(bp, bof0 + g * 4096, bof0x + g * 4096);
            #pragma unroll
            for (int t = 0; t < 4; ++t)
                acc[g][t] = __builtin_amdgcn_mfma_scale_f32_32x32x64_f8f6f4(
                    af[t], bf, acc[g][t],
                    0, 0,                     // cbsz=fp8(A), blgp=fp8(B)
                    0, 0x7F7F7F7F,            // A scale = 1.0
                    0, 0x7B7B7B7B);           // B scale = 2^-4 (w stored x16)
        }
    };

    constexpr int NC = D_ / BK;   // 16 chunks
    issue_loads(0);               //  7 in flight (chunk 0)
    issue_loads(1);               // 14 in flight (chunks 0,1)
    #pragma unroll
    for (int c = 0; c < NC - 1; ++c) {
        // chunk c ready; leave chunk c+1's 7 loads in flight
        asm volatile("s_waitcnt vmcnt(7)" ::: "memory");
        __builtin_amdgcn_s_barrier();
        __builtin_amdgcn_s_setprio(1);
        compute(c & 1);
        __builtin_amdgcn_s_setprio(0);
        // all this wave's ds_reads of buf (c&1) complete before the barrier,
        // so after it the buffer may be overwritten by anyone's DMA.
        asm volatile("s_waitcnt lgkmcnt(0)" ::: "memory");
        __builtin_amdgcn_sched_barrier(0);
        __builtin_amdgcn_s_barrier();
        if (c + 2 < NC) issue_loads(c & 1);
    }
    asm volatile("s_waitcnt vmcnt(0)" ::: "memory");
    __builtin_amdgcn_s_barrier();
    __builtin_amdgcn_s_setprio(1);
    compute((NC - 1) & 1);
    __builtin_amdgcn_s_setprio(0);

    // --- epilogue: exp-form chain + column (s) reduction ------------------
    // C/D 32x32 layout: col = lane&31, row = (reg&3) + 8*(reg>>2) + 4*half
    float vsum = 0.f;
    #pragma unroll
    for (int t = 0; t < 4; ++t) {
        f32x16 fv = acc[0][t], iv = acc[1][t], hv = acc[2][t];
        #pragma unroll
        for (int r = 0; r < 16; ++r) {
            float ef = __expf(-fv[r]);
            float ei = __expf(-iv[r]);
            float h  = hv[r];
            float eh = __expf(h);
            float g  = (h >= 0.f) ? (h + 0.5f)
                                  : (eh * __builtin_amdgcn_rcpf(1.f + eh));
            vsum += (1.f + ef) * __builtin_amdgcn_rcpf(1.f + ei) * g;
        }
    }
    vsum += __shfl_xor(vsum, 32, 64);
    if (half == 0) atomicAdd(&colsum[wn * 32 + l31], vsum);
    __syncthreads();
    if (tid < BN)
        atomicAdd(&acc_ws[(size_t)b * H_ + h0 + tid], colsum[tid]);
}

// out[b,o] = b_out[o] + sum_h w_out[o,h] * F[b,h]*(0.5 + acc[b,h])
__global__ __launch_bounds__(256) void out_gemv(
    const float* __restrict__ wout, const float* __restrict__ bout,
    const float* __restrict__ acc_ws, const float* __restrict__ F_ws,
    float* __restrict__ out)
{
    const int lane = threadIdx.x & 63;
    const int o = blockIdx.x * 4 + (threadIdx.x >> 6);
    float s[B_] = {};
    for (int h = lane; h < H_; h += 64) {
        float w = wout[(size_t)o * H_ + h];
        #pragma unroll
        for (int b = 0; b < B_; ++b) {
            float hv = F_ws[b * H_ + h] * (0.5f + acc_ws[b * H_ + h]);
            s[b] = fmaf(w, hv, s[b]);
        }
    }
    #pragma unroll
    for (int b = 0; b < B_; ++b)
        #pragma unroll
        for (int off = 32; off > 0; off >>= 1)
            s[b] += __shfl_down(s[b], off, 64);
    if (lane == 0) {
        float bo = bout[o];
        #pragma unroll
        for (int b = 0; b < B_; ++b)
            out[(size_t)b * O_ + o] = s[b] + bo;
    }
}

// ---------------------------------------------------------------------------
// fp32 fallback (round-1 kernel) -- used only if ws_size is too small
// ---------------------------------------------------------------------------
constexpr int TS = 64, TH = 64, TK = 16, LDP = 68;

__global__ __launch_bounds__(256) void fused_gemm_reduce(
    const float* __restrict__ x, const float* __restrict__ win,
    float* __restrict__ acc_ws, float* __restrict__ F_ws)
{
    __shared__ __align__(16) float As[TK][LDP];
    __shared__ __align__(16) float Wf[TK][LDP];
    __shared__ __align__(16) float Wi[TK][LDP];
    __shared__ __align__(16) float Wh[TK][LDP];
    __shared__ float colsum[TH];

    const int b  = blockIdx.z;
    const int s0 = blockIdx.x * TS;
    const int h0 = blockIdx.y * TH;
    const int tid = threadIdx.x;
    const int tx = tid & 15;
    const int ty = tid >> 4;

    float accf[4][4] = {};
    float acci[4][4] = {};
    float acch[4][4] = {};

    const int lrow = tid >> 2;
    const int lk4  = (tid & 3) << 2;

    const float* xp  = x   + ((size_t)b * S_ + (s0 + lrow)) * D_ + lk4;
    const float* wfp = win + (size_t)(h0 + lrow) * D_ + lk4;
    const float* wip = wfp + (size_t)H_ * D_;
    const float* whp = wip + (size_t)H_ * D_;

    for (int k0 = 0; k0 < D_; k0 += TK) {
        float4 va = *(const float4*)(xp  + k0);
        float4 vf = *(const float4*)(wfp + k0);
        float4 vi = *(const float4*)(wip + k0);
        float4 vh = *(const float4*)(whp + k0);
        __syncthreads();
        As[lk4+0][lrow]=va.x; As[lk4+1][lrow]=va.y; As[lk4+2][lrow]=va.z; As[lk4+3][lrow]=va.w;
        Wf[lk4+0][lrow]=vf.x; Wf[lk4+1][lrow]=vf.y; Wf[lk4+2][lrow]=vf.z; Wf[lk4+3][lrow]=vf.w;
        Wi[lk4+0][lrow]=vi.x; Wi[lk4+1][lrow]=vi.y; Wi[lk4+2][lrow]=vi.z; Wi[lk4+3][lrow]=vi.w;
        Wh[lk4+0][lrow]=vh.x; Wh[lk4+1][lrow]=vh.y; Wh[lk4+2][lrow]=vh.z; Wh[lk4+3][lrow]=vh.w;
        __syncthreads();
        #pragma unroll
        for (int k = 0; k < TK; ++k) {
            float4 a4 = *(const float4*)&As[k][ty << 2];
            float4 f4 = *(const float4*)&Wf[k][tx << 2];
            float4 i4 = *(const float4*)&Wi[k][tx << 2];
            float4 h4 = *(const float4*)&Wh[k][tx << 2];
            float a[4]  = {a4.x, a4.y, a4.z, a4.w};
            float wf[4] = {f4.x, f4.y, f4.z, f4.w};
            float wi[4] = {i4.x, i4.y, i4.z, i4.w};
            float wh[4] = {h4.x, h4.y, h4.z, h4.w};
            #pragma unroll
            for (int r = 0; r < 4; ++r)
                #pragma unroll
                for (int cc = 0; cc < 4; ++cc) {
                    accf[r][cc] = fmaf(a[r], wf[cc], accf[r][cc]);
                    acci[r][cc] = fmaf(a[r], wi[cc], acci[r][cc]);
                    acch[r][cc] = fmaf(a[r], wh[cc], acch[r][cc]);
                }
        }
    }

    const bool last_s = (s0 + TS == S_);
    float cval[4] = {0.f, 0.f, 0.f, 0.f};
    #pragma unroll
    for (int cc = 0; cc < 4; ++cc)
        #pragma unroll
        for (int r = 0; r < 4; ++r) {
            float f = accf[r][cc], i = acci[r][cc], h = acch[r][cc];
            float d  = softplusf(-f) - softplusf(-i);
            float lg = (h >= 0.f) ? logf(h + 0.5f) : -softplusf(-h);
            cval[cc] += expf(d + lg);
            if (last_s && ty == 15 && r == 3)
                F_ws[(size_t)b * H_ + h0 + (tx << 2) + cc] = expf(-softplusf(d));
        }
    if (tid < TH) colsum[tid] = 0.f;
    __syncthreads();
    #pragma unroll
    for (int cc = 0; cc < 4; ++cc)
        atomicAdd(&colsum[(tx << 2) + cc], cval[cc]);
    __syncthreads();
    if (tid < TH)
        atomicAdd(&acc_ws[(size_t)b * H_ + h0 + tid], colsum[tid]);
}

extern "C" void kernel_launch(void* const* d_in, const int* in_sizes, int n_in,
                              void* d_out, int out_size, void* d_ws, size_t ws_size,
                              hipStream_t stream) {
    const float* x    = (const float*)d_in[0];
    const float* w_in = (const float*)d_in[1];
    const float* wout = (const float*)d_in[2];
    const float* bout = (const float*)d_in[3];
    float* out = (float*)d_out;

    float* acc_ws = (float*)d_ws;                 // [B,H] running sums
    float* F_ws   = acc_ws + (size_t)B_ * H_;     // [B,H] exact forget factor

    hipMemsetAsync(d_ws, 0, 2 * (size_t)B_ * H_ * sizeof(float), stream);

    const size_t nx = (size_t)B_ * S_ * D_;       // 33.5M
    const size_t nw = (size_t)3 * H_ * D_;        // 3.1M
    const size_t q_off = 32768;                   // past acc/F, 16B aligned
    const size_t need = q_off + nx + nw;          // fp8: 1 byte/elem

    if (ws_size >= need) {
        unsigned char* xq = (unsigned char*)d_ws + q_off;
        unsigned char* wq = xq + nx;              // contiguous: wq = xq + NX
        int nx8 = (int)(nx / 8), nw8 = (int)(nw / 8);
        cvt_fp8_2<<<(nx8 + nw8 + 255) / 256, 256, 0, stream>>>(
            x, xq, nx8, w_in, wq, nw8);
        f_exact<<<B_ * H_ / 4, 256, 0, stream>>>(x, w_in, F_ws);
        gemm_fused_fp8<<<(H_ / BN) * (S_ / BM) * B_, 256, 0, stream>>>(
            xq, wq, acc_ws);
    } else {
        dim3 grid(S_ / TS, H_ / TH, B_);
        fused_gemm_reduce<<<grid, 256, 0, stream>>>(x, w_in, acc_ws, F_ws);
    }
    out_gemv<<<O_ / 4, 256, 0, stream>>>(wout, bout, acc_ws, F_ws, out);
}